// Round 8
// baseline (1457.109 us; speedup 1.0000x reference)
//
#include <hip/hip_runtime.h>

// NetG: seq2seq GRU (enc GRU -> +noise -> dec GRU -> FC head)
// B=512, T=256, H=256, D=3.
//
// R19b = R19 resubmitted verbatim (R7 bench died to a container/infra
//   failure before producing any data; static re-audit found no OOB/hang
//   path, and the numerics algebra was re-verified).
//
// R19 = LDS-traffic diet of R18. The per-CU LDS pipe is the binding pipe
//   (m134: ds_read_b128 ~12 cyc/CU): R17/R18 spent ~2600 cyc/CU/step on
//   LDS, mostly redundant reads of PAD columns and weight fragments.
//   R18's two regressions fixed:
//   a) scatter bank conflict (26.2M, 4-way: bank index lost c) -> XOR
//      swizzle off=(e^(e>>4))<<3: banks 16(q&1)+4(r^c)+j = 2-way (free).
//   b) gate-r k=4..7 global stream (64KB/block/step x 16 blocks/XCD
//      saturated L2) -> ALL W_hh fragments register-resident (Wf[3][8],
//      96 regs, MFMA-A operands). No prep_wr, no LDS weight staging, no
//      global weight stream.
//   c) h buffers compacted to NB=4 real cols (1024 shorts/parity) and
//      bf loads predicated on c<NB: each bf instr moves 256B not 1KB.
//      Compact layout idx(d,c) = (d>>3)*32 + c*8 + (d&7) reads dims
//      (4k+q)*8+s per (k,q,s) - algebraically identical to the proven
//      fragment order. X compacted to 4 cols likewise. LDS = 28.7 KB.
// Structure: 128 blocks x 1024 thr (16 waves, 4/SIMD), NB=4 real
// batches/block, wave owns hidden tile ht=w. Redistribution epilogue
// (R18): lanes c<4 scatter gate quads {r,z,nh,nx} to wave-private
// swizzled scratch; all 64 lanes finalize ONE value (6 trans/wave).
// Value-lane fp32 h carry (exact). One barrier/step.
// Frozen: bf16 GEMM operands, bias-column trick (q==0 A-lanes), native
// v_exp gates, x-step MFMA re-init between scatter and scratch read.

#define B_TOT 512
#define T_LEN 256
#define HID 256
#define NBATCH 16              // MFMA column count (cols >= NB are pad)
#define NB 4                   // real batches per block
#define NTHREADS 1024
#define NBLK (B_TOT / NB)      // 128

#define XSLOTS (T_LEN + 1)
#define XT 16                  // compact x slot: 4 cols x 4 shorts
#define HBUF (NB * HID)        // 1024 shorts per h parity buffer

// LDS partition (units: shorts)
#define H_OFF 0                          // 2 x 1024
#define X_OFF (2 * HBUF)                 // 2048
#define RD_OFF (X_OFF + XSLOTS * XT)     // 2048 + 4112 = 6160
#define SMEM_SHORTS (RD_OFF + 16 * 512)  // 14352
#define SMEM_BYTES  (SMEM_SHORTS * 2)    // 28704 B

typedef __attribute__((ext_vector_type(4))) float f32x4;
typedef __attribute__((ext_vector_type(8))) short shortx8;
typedef __attribute__((ext_vector_type(4))) short i16x4;
typedef __attribute__((ext_vector_type(4))) unsigned short ushortx4;
typedef __attribute__((ext_vector_type(8))) unsigned short ushortx8;

#if __has_builtin(__builtin_amdgcn_mfma_f32_16x16x16_bf16)
#define HAVE_K16 1
#define MFMA_X(A, B, C) __builtin_amdgcn_mfma_f32_16x16x16_bf16((A), (B), (C), 0, 0, 0)
#elif __has_builtin(__builtin_amdgcn_mfma_f32_16x16x16bf16_1k)
#define HAVE_K16 1
#define MFMA_X(A, B, C) __builtin_amdgcn_mfma_f32_16x16x16bf16_1k((A), (B), (C), 0, 0, 0)
#else
#define HAVE_K16 0
#endif

__device__ __forceinline__ unsigned short f2bf(float x) {
    unsigned u = __float_as_uint(x);
    u += 0x7FFF + ((u >> 16) & 1);   // RNE
    return (unsigned short)(u >> 16);
}
__device__ __forceinline__ float bf2f(unsigned short s) {
    return __uint_as_float(((unsigned)s) << 16);
}
__device__ __forceinline__ float fastrcp(float x) {
#if __has_builtin(__builtin_amdgcn_rcpf)
    return __builtin_amdgcn_rcpf(x);
#else
    return 1.0f / x;
#endif
}
__device__ __forceinline__ float exp2raw(float y) {
#if __has_builtin(__builtin_amdgcn_exp2f)
    return __builtin_amdgcn_exp2f(y);
#else
    return __expf(y * 0.69314718056f);
#endif
}
__device__ __forceinline__ float sigmoid_(float x) {
    return fastrcp(1.0f + exp2raw(x * -1.44269504f));
}
__device__ __forceinline__ float tanh_(float x) {
    return 2.0f * fastrcp(1.0f + exp2raw(x * -2.88539008f)) - 1.0f;
}

template<int IS_DEC>
__global__ __launch_bounds__(NTHREADS, 4) void gru_persistent(
    const float* __restrict__ X,       // [512][256][3]
    const float* __restrict__ W_hh,    // [768][256] gates r,z,n
    const float* __restrict__ W_ih,    // [768][3]
    const float* __restrict__ b_ih,    // [768]
    const float* __restrict__ b_hh,    // [768]
    const float* __restrict__ h_in,    // dec: [512][256] fp32; enc: null
    const float* __restrict__ noise,   // dec: [512][256]; enc: null
    float* __restrict__ h_out,         // enc: [512][256] fp32; dec: null
    unsigned short* __restrict__ Yout) // dec: [128][256][4][256] bf16
{
    extern __shared__ unsigned short smem[];
    unsigned short* shH  = smem + H_OFF;   // 2 compact parity buffers
    unsigned short* shX  = smem + X_OFF;
    unsigned short* shRd = smem + RD_OFF;

    const int tid  = threadIdx.x;
    const int g    = blockIdx.x;
    const int w    = tid >> 6;        // wave 0..15; owns hidden tile ht = w
    const int lane = tid & 63;
    const int c    = lane & 15;       // GEMM: A-row within tile / B batch col
    const int q    = lane >> 4;
    const int ht   = w;
    // value-lane mapping (epilogue): lane = cv*16 + din
    const int cv   = lane >> 4;       // real batch 0..3
    const int din  = lane & 15;       // dim within tile
    const int d_glob = ht * 16 + din;

    // ---- stage X into LDS (compact, 4 cols; shift baked in) ----
    for (int idx = tid; idx < NB * XSLOTS; idx += NTHREADS) {
        int t = idx >> 2, cc = idx & 3;
        int ts = IS_DEC ? (t - 1) : t;
        float x0 = 0.0f, x1 = 0.0f, x2 = 0.0f;
        if (ts >= 0 && ts < T_LEN) {
            const float* xp = X + ((size_t)(g * NB + cc) * T_LEN + ts) * 3;
            x0 = xp[0]; x1 = xp[1]; x2 = xp[2];
        }
        ushortx4 v = {f2bf(x0), f2bf(x1), f2bf(x2), (unsigned short)0x3F80};
        *(ushortx4*)&shX[t * XT + cc * 4] = v;
    }

    // ---- ALL three gates' A-frags resident (24 shortx8 = 96 regs) ----
    shortx8 Wf[3][8];   // [r|z|n][k]
    #pragma unroll
    for (int gg = 0; gg < 3; ++gg) {
        int row = gg * 256 + ht * 16 + c;
        const float* wp = W_hh + (size_t)row * 256 + q * 8;
        #pragma unroll
        for (int k = 0; k < 8; ++k) {
            const f32x4* p = (const f32x4*)(wp + k * 32);
            f32x4 f0 = p[0];
            f32x4 f1 = p[1];
            shortx8 a;
            a[0] = (short)f2bf(f0[0]); a[1] = (short)f2bf(f0[1]);
            a[2] = (short)f2bf(f0[2]); a[3] = (short)f2bf(f0[3]);
            a[4] = (short)f2bf(f1[0]); a[5] = (short)f2bf(f1[1]);
            a[6] = (short)f2bf(f1[2]); a[7] = (short)f2bf(f1[3]);
            Wf[gg][k] = a;
        }
    }

    // ---- x/bias A-frags (q==0 lanes carry data; others MUST be zero) ----
#if HAVE_K16
    i16x4 ax[3];
#else
    shortx8 ax[3];
#endif
    {
        int rr_ = ht * 16 + c;
        int rowr = rr_, rowz = 256 + rr_, rown = 512 + rr_;
        short r0 = 0, r1 = 0, r2 = 0, r3 = 0, z0 = 0, z1 = 0, z2 = 0, z3 = 0;
        short n0 = 0, n1 = 0, n2 = 0, n3 = 0;
        if (q == 0) {
            r0 = (short)f2bf(W_ih[rowr * 3 + 0]);
            r1 = (short)f2bf(W_ih[rowr * 3 + 1]);
            r2 = (short)f2bf(W_ih[rowr * 3 + 2]);
            r3 = (short)f2bf(b_ih[rowr] + b_hh[rowr]);
            z0 = (short)f2bf(W_ih[rowz * 3 + 0]);
            z1 = (short)f2bf(W_ih[rowz * 3 + 1]);
            z2 = (short)f2bf(W_ih[rowz * 3 + 2]);
            z3 = (short)f2bf(b_ih[rowz] + b_hh[rowz]);
            n0 = (short)f2bf(W_ih[rown * 3 + 0]);
            n1 = (short)f2bf(W_ih[rown * 3 + 1]);
            n2 = (short)f2bf(W_ih[rown * 3 + 2]);
            n3 = (short)f2bf(b_ih[rown]);
        }
#if HAVE_K16
        ax[0] = i16x4{r0, r1, r2, r3};
        ax[1] = i16x4{z0, z1, z2, z3};
        ax[2] = i16x4{n0, n1, n2, n3};
#else
        ax[0] = shortx8{r0, r1, r2, r3, 0, 0, 0, 0};
        ax[1] = shortx8{z0, z1, z2, z3, 0, 0, 0, 0};
        ax[2] = shortx8{n0, n1, n2, n3, 0, 0, 0, 0};
#endif
    }

    // ---- nh-bias register constants (b_hh n-gate, this lane's rows) ----
    f32x4 nhb = *(const f32x4*)(b_hh + 512 + ht * 16 + q * 4);

    // ---- compact h offset for this lane's value (batch cv, dim d_glob) ----
    const int offv = (d_glob >> 3) * 32 + cv * 8 + (d_glob & 7);

    // ---- init h0: value-lane fp32 carry; bf16 into parity buffer 0 ----
    // 1024 lanes cover all 1024 slots of buffer 0 exactly.
    float hold = 0.0f;
    if (IS_DEC) {
        int b = g * NB + cv;
        hold = h_in[(size_t)b * HID + d_glob] + noise[(size_t)b * HID + d_glob];
    }
    shH[offv] = f2bf(hold);

    // ---- incremental decoder Y pointer (step stride = NB*HID shorts) ----
    unsigned short* yp = nullptr;
    if (IS_DEC)
        yp = Yout + ((size_t)g * T_LEN * NB + cv) * HID + d_glob;

    __syncthreads();

    const f32x4 zc = {0.0f, 0.0f, 0.0f, 0.0f};
    const shortx8 z8 = {0, 0, 0, 0, 0, 0, 0, 0};

    // ---- x-step for t=0 (C = inline 0 initializes acc r/z/nx) ----
    f32x4 acc0, acc1, acc2, acc3;   // r, z, nh, nx
    {
#if HAVE_K16
        i16x4 bx = {0, 0, 0, 0};
        if (c < NB) bx = *(const i16x4*)&shX[c * 4];
        acc0 = MFMA_X(ax[0], bx, zc);
        acc1 = MFMA_X(ax[1], bx, zc);
        acc3 = MFMA_X(ax[2], bx, zc);
#else
        shortx8 bx = z8;
        if (q == 0 && c < NB) {
            ushortx4 xv = *(const ushortx4*)&shX[c * 4];
            bx = shortx8{(short)xv[0], (short)xv[1], (short)xv[2], (short)xv[3],
                         0, 0, 0, 0};
        }
        acc0 = __builtin_amdgcn_mfma_f32_16x16x32_bf16(ax[0], bx, zc, 0, 0, 0);
        acc1 = __builtin_amdgcn_mfma_f32_16x16x32_bf16(ax[1], bx, zc, 0, 0, 0);
        acc3 = __builtin_amdgcn_mfma_f32_16x16x32_bf16(ax[2], bx, zc, 0, 0, 0);
#endif
    }

    const int bbase = q * 32 + c * 8;    // lane's compact B-frag base (c<NB)
    unsigned short* shRd_w = shRd + w * 512;  // wave-private 1KB scratch
    // swizzled scratch offsets (shorts): off(e) = (e ^ (e>>4)) << 3
    const int rdoff = ((lane ^ (lane >> 4)) << 3);

    int xidx = XT + c * 4;   // x slot for step t+1 (only read when c<NB)

    // ---- recurrence ----
    for (int t = 0; t < T_LEN; ++t) {
        const unsigned short* brow = shH + (t & 1) * HBUF + bbase;
        unsigned short* hn = shH + ((t + 1) & 1) * HBUF;

        // n-gate hidden accumulator starts from the b_hh bias constants
        acc2 = nhb;

        // GEMM: all A-frags from regs; B-frags predicated (pad cols = 0
        // from regs -> each ds_read moves 256B, 4x less LDS-pipe time)
        #pragma unroll
        for (int k = 0; k < 8; ++k) {
            shortx8 bf = z8;
            if (c < NB) bf = *(const shortx8*)(brow + k * 128);
            acc0 = __builtin_amdgcn_mfma_f32_16x16x32_bf16(Wf[0][k], bf, acc0, 0, 0, 0);
            acc1 = __builtin_amdgcn_mfma_f32_16x16x32_bf16(Wf[1][k], bf, acc1, 0, 0, 0);
            acc2 = __builtin_amdgcn_mfma_f32_16x16x32_bf16(Wf[2][k], bf, acc2, 0, 0, 0);
        }

        // ---- scatter gate quads to swizzled wave-private scratch ----
        // entry e = c*16 + q*4 + r; banks 16(q&1)+4(r^c)+j -> 2-way (free)
        if (c < NB) {
            #pragma unroll
            for (int r = 0; r < 4; ++r) {
                f32x4 v = {acc0[r], acc1[r], acc2[r], acc3[r]};
                int e = c * 16 + q * 4 + r;
                *(f32x4*)&shRd_w[(e ^ c) << 3] = v;
            }
        }

        // bx for step t+1
#if HAVE_K16
        i16x4 bxn = {0, 0, 0, 0};
        if (c < NB) bxn = *(const i16x4*)&shX[xidx];
#else
        shortx8 bxn = z8;
        if (q == 0 && c < NB) {
            ushortx4 xvn = *(const ushortx4*)&shX[xidx];
            bxn = shortx8{(short)xvn[0], (short)xvn[1], (short)xvn[2], (short)xvn[3],
                          0, 0, 0, 0};
        }
#endif
        xidx += XT;

        // x-step re-init for t+1 (independent MFMAs hide the lgkm wait)
#if HAVE_K16
        acc0 = MFMA_X(ax[0], bxn, zc);
        acc1 = MFMA_X(ax[1], bxn, zc);
        acc3 = MFMA_X(ax[2], bxn, zc);
#else
        acc0 = __builtin_amdgcn_mfma_f32_16x16x32_bf16(ax[0], bxn, zc, 0, 0, 0);
        acc1 = __builtin_amdgcn_mfma_f32_16x16x32_bf16(ax[1], bxn, zc, 0, 0, 0);
        acc3 = __builtin_amdgcn_mfma_f32_16x16x32_bf16(ax[2], bxn, zc, 0, 0, 0);
#endif

        // ---- value-lane epilogue: ONE value per lane (6 trans/wave) ----
        {
            f32x4 av = *(const f32x4*)&shRd_w[rdoff];   // {r,z,nh,nx}
            float rr = sigmoid_(av[0]);
            float zz = sigmoid_(av[1]);
            float nn = tanh_(av[3] + rr * av[2]);
            float ho = nn + zz * (hold - nn);
            hold = ho;
            unsigned short hb = f2bf(ho);
            hn[offv] = hb;
            if (IS_DEC) {
                *yp = hb;
                yp += NB * HID;   // stride NB*256 shorts per step
            }
        }
        __syncthreads();
    }

    if (!IS_DEC) {
        // hand the decoder the EXACT fp32 final h (value-lane scalar store)
        h_out[(size_t)(g * NB + cv) * HID + d_glob] = hold;
    }
}

// out[b][t][d] = sum_h Y[g][t][b4][h] * W_fc[d][h] + b_fc[d]
// Y layout: [128][256][4][256]
__global__ __launch_bounds__(256) void proj_kernel(
    const unsigned short* __restrict__ Y, const float* __restrict__ W_fc,
    const float* __restrict__ b_fc, float* __restrict__ out)
{
    int row = blockIdx.x * 256 + threadIdx.x;  // ((g*T + t)*NB + b4)
    int b4 = row & (NB - 1);
    int gt = row >> 2;                         // g*T + t
    int t = gt & (T_LEN - 1);
    int g = gt >> 8;
    const unsigned short* y = Y + (size_t)row * HID;
    float a0 = b_fc[0], a1 = b_fc[1], a2 = b_fc[2];
    #pragma unroll 4
    for (int k8 = 0; k8 < 32; ++k8) {
        ushortx8 v = *(const ushortx8*)(y + k8 * 8);
        #pragma unroll
        for (int j = 0; j < 8; ++j) {
            float f = bf2f(v[j]);
            int k = k8 * 8 + j;
            a0 += f * W_fc[k];          // uniform -> scalar loads
            a1 += f * W_fc[256 + k];
            a2 += f * W_fc[512 + k];
        }
    }
    int batch = g * NB + b4;
    float* o = out + ((size_t)batch * T_LEN + t) * 3;
    o[0] = a0; o[1] = a1; o[2] = a2;
}

extern "C" void kernel_launch(void* const* d_in, const int* in_sizes, int n_in,
                              void* d_out, int out_size, void* d_ws, size_t ws_size,
                              hipStream_t stream)
{
    const float* X_p      = (const float*)d_in[0];
    const float* X_f      = (const float*)d_in[1];
    const float* noise    = (const float*)d_in[2];
    const float* W_ih_enc = (const float*)d_in[3];
    const float* W_hh_enc = (const float*)d_in[4];
    const float* b_ih_enc = (const float*)d_in[5];
    const float* b_hh_enc = (const float*)d_in[6];
    const float* W_ih_dec = (const float*)d_in[7];
    const float* W_hh_dec = (const float*)d_in[8];
    const float* b_ih_dec = (const float*)d_in[9];
    const float* b_hh_dec = (const float*)d_in[10];
    const float* W_fc     = (const float*)d_in[11];
    const float* b_fc     = (const float*)d_in[12];

    // ws: [0,512K) h_enc fp32 | [512K, +67.1MB) decoder Y bf16
    float* h_enc = (float*)d_ws;
    unsigned short* Yws = (unsigned short*)((char*)d_ws + (512u << 10));

    hipLaunchKernelGGL((gru_persistent<0>), dim3(NBLK), dim3(NTHREADS), SMEM_BYTES, stream,
        X_p, W_hh_enc, W_ih_enc, b_ih_enc, b_hh_enc,
        (const float*)nullptr, (const float*)nullptr, h_enc,
        (unsigned short*)nullptr);

    hipLaunchKernelGGL((gru_persistent<1>), dim3(NBLK), dim3(NTHREADS), SMEM_BYTES, stream,
        X_f, W_hh_dec, W_ih_dec, b_ih_dec, b_hh_dec,
        h_enc, noise, (float*)nullptr, Yws);

    hipLaunchKernelGGL(proj_kernel, dim3((B_TOT * T_LEN) / 256), dim3(256), 0, stream,
        Yws, W_fc, b_fc, (float*)d_out);
}

// Round 9
// 1206.630 us; speedup vs baseline: 1.2076x; 1.2076x over previous
//
#include <hip/hip_runtime.h>

// NetG: seq2seq GRU (enc GRU -> +noise -> dec GRU -> FC head)
// B=512, T=256, H=256, D=3.
//
// R20 = full-residency fat waves at 2/SIMD + R19's verified LDS diet.
//   R19 post-mortem: 16-wave blocks force 4 waves/SIMD -> 128-reg unified
//   budget; Wf[3][8]=96 + state ~145 regs -> compiler spilled to scratch
//   (VGPR=64, encoder WRITE_SIZE 164MB of spill traffic, 730us). The
//   swizzled scratch + compact-h pieces measured CLEAN (bank conflicts=0).
//   Fix: 512 thr / 8 waves, 2 tiles/wave -> 2 waves/SIMD -> 256-reg
//   budget; Wf[2][3][8]=192 fully resident fits (R12 precedent at
//   2/SIMD). Zero weight traffic: no prep_wr, no global stream, no LDS
//   weight reads. MFMA floor 432x4.85 ~= 2100 cyc/CU/step dominates.
// Structure: 128 blocks x 512 thr, NB=4 real batches/block. Wave owns
// tiles {w, w+8} x 3 gates. Compact h [2 parity][1024] (predicated 256B
// bf reads), compact x, swizzled wave-private scatter/gather epilogue:
// GEMM lanes c<4 scatter gate quads {r,z,nh,nx}; every lane finalizes 2
// values (12 trans/wave). fp32 value-lane h carry (exact). b_hhn added
// in the fp32 epilogue (not C-init) - same math, 4 fewer regs.
// Frozen: bf16 GEMM operands, bias-column trick (q==0 A-lanes carry
// x/bias via K16 MFMA), native v_exp gates, x-step MFMA re-init between
// scatter and gather, one barrier per step, incremental Y pointer.

#define B_TOT 512
#define T_LEN 256
#define HID 256
#define NBATCH 16              // MFMA column count (cols >= NB are pad)
#define NB 4                   // real batches per block
#define NTHREADS 512           // 8 waves, 2 tiles/wave
#define NBLK (B_TOT / NB)      // 128

#define XSLOTS (T_LEN + 1)
#define XT 16                  // compact x slot: 4 cols x 4 shorts
#define HBUF (NB * HID)        // 1024 shorts per h parity buffer

// LDS partition (units: shorts)
#define H_OFF 0                          // 2 x 1024
#define X_OFF (2 * HBUF)                 // 2048
#define RD_OFF (X_OFF + XSLOTS * XT)     // 2048 + 4112 = 6160
#define SMEM_SHORTS (RD_OFF + 8 * 1024)  // + 8 waves x 2KB scratch = 14352
#define SMEM_BYTES  (SMEM_SHORTS * 2)    // 28704 B

typedef __attribute__((ext_vector_type(4))) float f32x4;
typedef __attribute__((ext_vector_type(8))) short shortx8;
typedef __attribute__((ext_vector_type(4))) short i16x4;
typedef __attribute__((ext_vector_type(4))) unsigned short ushortx4;
typedef __attribute__((ext_vector_type(8))) unsigned short ushortx8;

#if __has_builtin(__builtin_amdgcn_mfma_f32_16x16x16_bf16)
#define HAVE_K16 1
#define MFMA_X(A, B, C) __builtin_amdgcn_mfma_f32_16x16x16_bf16((A), (B), (C), 0, 0, 0)
#elif __has_builtin(__builtin_amdgcn_mfma_f32_16x16x16bf16_1k)
#define HAVE_K16 1
#define MFMA_X(A, B, C) __builtin_amdgcn_mfma_f32_16x16x16bf16_1k((A), (B), (C), 0, 0, 0)
#else
#define HAVE_K16 0
#endif

__device__ __forceinline__ unsigned short f2bf(float x) {
    unsigned u = __float_as_uint(x);
    u += 0x7FFF + ((u >> 16) & 1);   // RNE
    return (unsigned short)(u >> 16);
}
__device__ __forceinline__ float bf2f(unsigned short s) {
    return __uint_as_float(((unsigned)s) << 16);
}
__device__ __forceinline__ float fastrcp(float x) {
#if __has_builtin(__builtin_amdgcn_rcpf)
    return __builtin_amdgcn_rcpf(x);
#else
    return 1.0f / x;
#endif
}
__device__ __forceinline__ float exp2raw(float y) {
#if __has_builtin(__builtin_amdgcn_exp2f)
    return __builtin_amdgcn_exp2f(y);
#else
    return __expf(y * 0.69314718056f);
#endif
}
__device__ __forceinline__ float sigmoid_(float x) {
    return fastrcp(1.0f + exp2raw(x * -1.44269504f));
}
__device__ __forceinline__ float tanh_(float x) {
    return 2.0f * fastrcp(1.0f + exp2raw(x * -2.88539008f)) - 1.0f;
}

template<int IS_DEC>
__global__ __launch_bounds__(NTHREADS, 2) void gru_persistent(
    const float* __restrict__ X,       // [512][256][3]
    const float* __restrict__ W_hh,    // [768][256] gates r,z,n
    const float* __restrict__ W_ih,    // [768][3]
    const float* __restrict__ b_ih,    // [768]
    const float* __restrict__ b_hh,    // [768]
    const float* __restrict__ h_in,    // dec: [512][256] fp32; enc: null
    const float* __restrict__ noise,   // dec: [512][256]; enc: null
    float* __restrict__ h_out,         // enc: [512][256] fp32; dec: null
    unsigned short* __restrict__ Yout) // dec: [128][256][4][256] bf16
{
    extern __shared__ unsigned short smem[];
    unsigned short* shH  = smem + H_OFF;   // 2 compact parity buffers
    unsigned short* shX  = smem + X_OFF;
    unsigned short* shRd = smem + RD_OFF;

    const int tid  = threadIdx.x;
    const int g    = blockIdx.x;
    const int w    = tid >> 6;        // wave 0..7; owns tiles {w, w+8}
    const int lane = tid & 63;
    const int c    = lane & 15;       // GEMM: A-row within tile / B batch col
    const int q    = lane >> 4;
    // value-lane mapping (epilogue): lane = cv*16 + din
    const int cv   = q;               // real batch 0..3
    const int din  = c;               // dim within tile

    // ---- stage X into LDS (compact, 4 cols; shift baked in) ----
    for (int idx = tid; idx < NB * XSLOTS; idx += NTHREADS) {
        int t = idx >> 2, cc = idx & 3;
        int ts = IS_DEC ? (t - 1) : t;
        float x0 = 0.0f, x1 = 0.0f, x2 = 0.0f;
        if (ts >= 0 && ts < T_LEN) {
            const float* xp = X + ((size_t)(g * NB + cc) * T_LEN + ts) * 3;
            x0 = xp[0]; x1 = xp[1]; x2 = xp[2];
        }
        ushortx4 v = {f2bf(x0), f2bf(x1), f2bf(x2), (unsigned short)0x3F80};
        *(ushortx4*)&shX[t * XT + cc * 4] = v;
    }

    // ---- ALL weights resident: 2 tiles x 3 gates x 8 k = 192 regs ----
    shortx8 Wf[2][3][8];   // [hti][r|z|n][k]
    #pragma unroll
    for (int hti = 0; hti < 2; ++hti) {
        int ht = w + hti * 8;
        #pragma unroll
        for (int gg = 0; gg < 3; ++gg) {
            int row = gg * 256 + ht * 16 + c;
            const float* wp = W_hh + (size_t)row * 256 + q * 8;
            #pragma unroll
            for (int k = 0; k < 8; ++k) {
                const f32x4* p = (const f32x4*)(wp + k * 32);
                f32x4 f0 = p[0];
                f32x4 f1 = p[1];
                shortx8 a;
                a[0] = (short)f2bf(f0[0]); a[1] = (short)f2bf(f0[1]);
                a[2] = (short)f2bf(f0[2]); a[3] = (short)f2bf(f0[3]);
                a[4] = (short)f2bf(f1[0]); a[5] = (short)f2bf(f1[1]);
                a[6] = (short)f2bf(f1[2]); a[7] = (short)f2bf(f1[3]);
                Wf[hti][gg][k] = a;
            }
        }
    }

    // ---- x/bias A-frags (q==0 lanes carry data; others MUST be zero) ----
#if HAVE_K16
    i16x4 ax[2][3];
#else
    shortx8 ax[2][3];
#endif
    #pragma unroll
    for (int hti = 0; hti < 2; ++hti) {
        int ht = w + hti * 8;
        int rr_ = ht * 16 + c;
        int rowr = rr_, rowz = 256 + rr_, rown = 512 + rr_;
        short r0 = 0, r1 = 0, r2 = 0, r3 = 0, z0 = 0, z1 = 0, z2 = 0, z3 = 0;
        short n0 = 0, n1 = 0, n2 = 0, n3 = 0;
        if (q == 0) {
            r0 = (short)f2bf(W_ih[rowr * 3 + 0]);
            r1 = (short)f2bf(W_ih[rowr * 3 + 1]);
            r2 = (short)f2bf(W_ih[rowr * 3 + 2]);
            r3 = (short)f2bf(b_ih[rowr] + b_hh[rowr]);
            z0 = (short)f2bf(W_ih[rowz * 3 + 0]);
            z1 = (short)f2bf(W_ih[rowz * 3 + 1]);
            z2 = (short)f2bf(W_ih[rowz * 3 + 2]);
            z3 = (short)f2bf(b_ih[rowz] + b_hh[rowz]);
            n0 = (short)f2bf(W_ih[rown * 3 + 0]);
            n1 = (short)f2bf(W_ih[rown * 3 + 1]);
            n2 = (short)f2bf(W_ih[rown * 3 + 2]);
            n3 = (short)f2bf(b_ih[rown]);
        }
#if HAVE_K16
        ax[hti][0] = i16x4{r0, r1, r2, r3};
        ax[hti][1] = i16x4{z0, z1, z2, z3};
        ax[hti][2] = i16x4{n0, n1, n2, n3};
#else
        ax[hti][0] = shortx8{r0, r1, r2, r3, 0, 0, 0, 0};
        ax[hti][1] = shortx8{z0, z1, z2, z3, 0, 0, 0, 0};
        ax[hti][2] = shortx8{n0, n1, n2, n3, 0, 0, 0, 0};
#endif
    }

    // ---- value-lane constants: n-gate hidden bias + h offsets ----
    float bhn[2];
    int offv[2];
    #pragma unroll
    for (int j = 0; j < 2; ++j) {
        int d = (w + j * 8) * 16 + din;
        bhn[j] = b_hh[512 + d];
        offv[j] = (d >> 3) * 32 + cv * 8 + (d & 7);
    }

    // ---- init h0: value-lane fp32 carry; bf16 into parity buffer 0 ----
    // 512 lanes x 2 values cover all 1024 slots of buffer 0 exactly.
    float hold[2] = {0.0f, 0.0f};
    #pragma unroll
    for (int j = 0; j < 2; ++j) {
        if (IS_DEC) {
            int d = (w + j * 8) * 16 + din;
            size_t gi = (size_t)(g * NB + cv) * HID + d;
            hold[j] = h_in[gi] + noise[gi];
        }
        shH[offv[j]] = f2bf(hold[j]);
    }

    // ---- incremental decoder Y pointer (step stride = NB*HID shorts) ----
    unsigned short* yp = nullptr;
    if (IS_DEC)
        yp = Yout + ((size_t)g * T_LEN * NB + cv) * HID + w * 16 + din;

    __syncthreads();

    const f32x4 zc = {0.0f, 0.0f, 0.0f, 0.0f};
    const shortx8 z8 = {0, 0, 0, 0, 0, 0, 0, 0};

    // ---- x-step for t=0 (C = inline 0 initializes acc r/z/nx) ----
    f32x4 acc[2][4];   // [hti][r, z, nh, nx]
    {
#if HAVE_K16
        i16x4 bx = {0, 0, 0, 0};
        if (c < NB) bx = *(const i16x4*)&shX[c * 4];
        #pragma unroll
        for (int hti = 0; hti < 2; ++hti) {
            acc[hti][0] = MFMA_X(ax[hti][0], bx, zc);
            acc[hti][1] = MFMA_X(ax[hti][1], bx, zc);
            acc[hti][3] = MFMA_X(ax[hti][2], bx, zc);
        }
#else
        shortx8 bx = z8;
        if (q == 0 && c < NB) {
            ushortx4 xv = *(const ushortx4*)&shX[c * 4];
            bx = shortx8{(short)xv[0], (short)xv[1], (short)xv[2], (short)xv[3],
                         0, 0, 0, 0};
        }
        #pragma unroll
        for (int hti = 0; hti < 2; ++hti) {
            acc[hti][0] = __builtin_amdgcn_mfma_f32_16x16x32_bf16(ax[hti][0], bx, zc, 0, 0, 0);
            acc[hti][1] = __builtin_amdgcn_mfma_f32_16x16x32_bf16(ax[hti][1], bx, zc, 0, 0, 0);
            acc[hti][3] = __builtin_amdgcn_mfma_f32_16x16x32_bf16(ax[hti][2], bx, zc, 0, 0, 0);
        }
#endif
    }

    const int bbase = q * 32 + c * 8;    // lane's compact B-frag base (c<NB)
    unsigned short* shRd_w = shRd + w * 1024;  // wave-private 2KB scratch
    // swizzled gather offsets per tile: e' = cv*16+din; addr = (e'^cv)<<3
    const int rdoff = (((cv * 16 + din) ^ cv) << 3);

    int xidx = XT + c * 4;   // x slot for step t+1 (only read when c<NB)

    // ---- recurrence ----
    for (int t = 0; t < T_LEN; ++t) {
        const unsigned short* brow = shH + (t & 1) * HBUF + bbase;
        unsigned short* hn = shH + ((t + 1) & 1) * HBUF;

        // n-gate accumulators start at 0 (b_hhn added in the epilogue)
        acc[0][2] = zc;
        acc[1][2] = zc;

        // GEMM: all A-frags from regs; shared B-frag predicated (256B/read)
        #pragma unroll
        for (int k = 0; k < 8; ++k) {
            shortx8 bf = z8;
            if (c < NB) bf = *(const shortx8*)(brow + k * 128);
            acc[0][0] = __builtin_amdgcn_mfma_f32_16x16x32_bf16(Wf[0][0][k], bf, acc[0][0], 0, 0, 0);
            acc[1][0] = __builtin_amdgcn_mfma_f32_16x16x32_bf16(Wf[1][0][k], bf, acc[1][0], 0, 0, 0);
            acc[0][1] = __builtin_amdgcn_mfma_f32_16x16x32_bf16(Wf[0][1][k], bf, acc[0][1], 0, 0, 0);
            acc[1][1] = __builtin_amdgcn_mfma_f32_16x16x32_bf16(Wf[1][1][k], bf, acc[1][1], 0, 0, 0);
            acc[0][2] = __builtin_amdgcn_mfma_f32_16x16x32_bf16(Wf[0][2][k], bf, acc[0][2], 0, 0, 0);
            acc[1][2] = __builtin_amdgcn_mfma_f32_16x16x32_bf16(Wf[1][2][k], bf, acc[1][2], 0, 0, 0);
        }

        // ---- scatter gate quads to swizzled wave-private scratch ----
        // tile region j*512 shorts; entry e = c*16 + q*4 + r, addr (e^c)<<3
        if (c < NB) {
            #pragma unroll
            for (int j = 0; j < 2; ++j) {
                #pragma unroll
                for (int r = 0; r < 4; ++r) {
                    f32x4 v = {acc[j][0][r], acc[j][1][r], acc[j][2][r], acc[j][3][r]};
                    int e = c * 16 + q * 4 + r;
                    *(f32x4*)&shRd_w[j * 512 + ((e ^ c) << 3)] = v;
                }
            }
        }

        // bx for step t+1
#if HAVE_K16
        i16x4 bxn = {0, 0, 0, 0};
        if (c < NB) bxn = *(const i16x4*)&shX[xidx];
#else
        shortx8 bxn = z8;
        if (q == 0 && c < NB) {
            ushortx4 xvn = *(const ushortx4*)&shX[xidx];
            bxn = shortx8{(short)xvn[0], (short)xvn[1], (short)xvn[2], (short)xvn[3],
                          0, 0, 0, 0};
        }
#endif
        xidx += XT;

        // x-step re-init for t+1 (independent MFMAs hide the lgkm wait)
#if HAVE_K16
        #pragma unroll
        for (int hti = 0; hti < 2; ++hti) {
            acc[hti][0] = MFMA_X(ax[hti][0], bxn, zc);
            acc[hti][1] = MFMA_X(ax[hti][1], bxn, zc);
            acc[hti][3] = MFMA_X(ax[hti][2], bxn, zc);
        }
#else
        #pragma unroll
        for (int hti = 0; hti < 2; ++hti) {
            acc[hti][0] = __builtin_amdgcn_mfma_f32_16x16x32_bf16(ax[hti][0], bxn, zc, 0, 0, 0);
            acc[hti][1] = __builtin_amdgcn_mfma_f32_16x16x32_bf16(ax[hti][1], bxn, zc, 0, 0, 0);
            acc[hti][3] = __builtin_amdgcn_mfma_f32_16x16x32_bf16(ax[hti][2], bxn, zc, 0, 0, 0);
        }
#endif

        // ---- value-lane epilogue: TWO values per lane (12 trans/wave) ----
        #pragma unroll
        for (int j = 0; j < 2; ++j) {
            f32x4 av = *(const f32x4*)&shRd_w[j * 512 + rdoff];  // {r,z,nh,nx}
            float rr = sigmoid_(av[0]);
            float zz = sigmoid_(av[1]);
            float nn = tanh_(av[3] + rr * (av[2] + bhn[j]));
            float ho = nn + zz * (hold[j] - nn);
            hold[j] = ho;
            unsigned short hb = f2bf(ho);
            hn[offv[j]] = hb;
            if (IS_DEC) yp[j * 128] = hb;
        }
        if (IS_DEC) yp += NB * HID;   // stride NB*256 shorts per step
        __syncthreads();
    }

    if (!IS_DEC) {
        // hand the decoder the EXACT fp32 final h (value-lane stores)
        #pragma unroll
        for (int j = 0; j < 2; ++j) {
            int d = (w + j * 8) * 16 + din;
            h_out[(size_t)(g * NB + cv) * HID + d] = hold[j];
        }
    }
}

// out[b][t][d] = sum_h Y[g][t][b4][h] * W_fc[d][h] + b_fc[d]
// Y layout: [128][256][4][256]
__global__ __launch_bounds__(256) void proj_kernel(
    const unsigned short* __restrict__ Y, const float* __restrict__ W_fc,
    const float* __restrict__ b_fc, float* __restrict__ out)
{
    int row = blockIdx.x * 256 + threadIdx.x;  // ((g*T + t)*NB + b4)
    int b4 = row & (NB - 1);
    int gt = row >> 2;                         // g*T + t
    int t = gt & (T_LEN - 1);
    int g = gt >> 8;
    const unsigned short* y = Y + (size_t)row * HID;
    float a0 = b_fc[0], a1 = b_fc[1], a2 = b_fc[2];
    #pragma unroll 4
    for (int k8 = 0; k8 < 32; ++k8) {
        ushortx8 v = *(const ushortx8*)(y + k8 * 8);
        #pragma unroll
        for (int j = 0; j < 8; ++j) {
            float f = bf2f(v[j]);
            int k = k8 * 8 + j;
            a0 += f * W_fc[k];          // uniform -> scalar loads
            a1 += f * W_fc[256 + k];
            a2 += f * W_fc[512 + k];
        }
    }
    int batch = g * NB + b4;
    float* o = out + ((size_t)batch * T_LEN + t) * 3;
    o[0] = a0; o[1] = a1; o[2] = a2;
}

extern "C" void kernel_launch(void* const* d_in, const int* in_sizes, int n_in,
                              void* d_out, int out_size, void* d_ws, size_t ws_size,
                              hipStream_t stream)
{
    const float* X_p      = (const float*)d_in[0];
    const float* X_f      = (const float*)d_in[1];
    const float* noise    = (const float*)d_in[2];
    const float* W_ih_enc = (const float*)d_in[3];
    const float* W_hh_enc = (const float*)d_in[4];
    const float* b_ih_enc = (const float*)d_in[5];
    const float* b_hh_enc = (const float*)d_in[6];
    const float* W_ih_dec = (const float*)d_in[7];
    const float* W_hh_dec = (const float*)d_in[8];
    const float* b_ih_dec = (const float*)d_in[9];
    const float* b_hh_dec = (const float*)d_in[10];
    const float* W_fc     = (const float*)d_in[11];
    const float* b_fc     = (const float*)d_in[12];

    // ws: [0,512K) h_enc fp32 | [512K, +67.1MB) decoder Y bf16
    float* h_enc = (float*)d_ws;
    unsigned short* Yws = (unsigned short*)((char*)d_ws + (512u << 10));

    hipLaunchKernelGGL((gru_persistent<0>), dim3(NBLK), dim3(NTHREADS), SMEM_BYTES, stream,
        X_p, W_hh_enc, W_ih_enc, b_ih_enc, b_hh_enc,
        (const float*)nullptr, (const float*)nullptr, h_enc,
        (unsigned short*)nullptr);

    hipLaunchKernelGGL((gru_persistent<1>), dim3(NBLK), dim3(NTHREADS), SMEM_BYTES, stream,
        X_f, W_hh_dec, W_ih_dec, b_ih_dec, b_hh_dec,
        h_enc, noise, (float*)nullptr, Yws);

    hipLaunchKernelGGL(proj_kernel, dim3((B_TOT * T_LEN) / 256), dim3(256), 0, stream,
        Yws, W_fc, b_fc, (float*)d_out);
}